// Round 13
// baseline (2160.787 us; speedup 1.0000x reference)
//
#include <hip/hip_runtime.h>
#include <hip/hip_bf16.h>
#include <math.h>

// Problem constants
#define BB 16
#define LL 512
#define DD 512
#define DD2 1024
#define KMIX 8
#define LPAD 520          // L + 8 pad rows (4 each side) for KS=9 conv
#define GRU_KSTEPS 33     // Wp layout keeps 33 k-steps; scan uses 0..31 (bias via scalars)

typedef __attribute__((ext_vector_type(8))) short short8;
typedef __attribute__((ext_vector_type(4))) float f32x4;
typedef unsigned short ushort;

__device__ __forceinline__ float bf2f(ushort u) {
  union { float f; unsigned i; } v; v.i = ((unsigned)u) << 16; return v.f;
}
__device__ __forceinline__ ushort f2bf(float f) {
  union { float f; unsigned i; } v; v.f = f;
  unsigned i = v.i;
  unsigned r = i + 0x7FFF + ((i >> 16) & 1);   // RNE
  return (ushort)(r >> 16);
}

// ---------------------------------------------------------------------------
// Elementwise prep kernels (grid-stride) — unchanged
// ---------------------------------------------------------------------------
__global__ void k_zero_bf16(ushort* p, long n) {
  for (long i = blockIdx.x * 256 + threadIdx.x; i < n; i += (long)gridDim.x * 256) p[i] = 0;
}
__global__ void k_fill_xpad(const float* __restrict__ x, ushort* __restrict__ xp) {
  const long n = (long)BB * LPAD * DD;
  for (long i = blockIdx.x * 256 + threadIdx.x; i < n; i += (long)gridDim.x * 256) {
    int d = (int)(i & 511);
    long rest = i >> 9;
    int p = (int)(rest % LPAD);
    int b = (int)(rest / LPAD);
    float v = 0.f;
    if (p >= 4 && p < 516) v = x[((long)b * LL + (p - 4)) * DD + d];
    xp[i] = f2bf(v);
  }
}
__global__ void k_pack_convw(const float* __restrict__ w, ushort* __restrict__ wp) {
  const long n = (long)DD * DD * 9;
  for (long idx = blockIdx.x * 256 + threadIdx.x; idx < n; idx += (long)gridDim.x * 256) {
    int i = (int)(idx & 511);
    int o = (int)((idx >> 9) & 511);
    int k = (int)(idx >> 18);
    wp[idx] = f2bf(w[((long)o * DD + i) * 9 + k]);
  }
}
__global__ void k_pack_wihx(const float* __restrict__ w_ih, ushort* __restrict__ wp) {
  const long n = (long)3 * DD2 * DD;
  for (long idx = blockIdx.x * 256 + threadIdx.x; idx < n; idx += (long)gridDim.x * 256) {
    int i = (int)(idx & 511);
    int nr = (int)(idx >> 9);
    wp[idx] = f2bf(w_ih[(long)nr * 1536 + i]);
  }
}
__global__ void k_pack_bf16(const float* __restrict__ s, ushort* __restrict__ d, long n) {
  for (long i = blockIdx.x * 256 + threadIdx.x; i < n; i += (long)gridDim.x * 256) d[i] = f2bf(s[i]);
}
__global__ void k_pack_gru(const float* __restrict__ w_ih, const float* __restrict__ w_hh,
                           const float* __restrict__ b_hh, ushort* __restrict__ wp) {
  const long n = (long)64 * 6 * GRU_KSTEPS * 64 * 8;
  for (long idx = blockIdx.x * 256 + threadIdx.x; idx < n; idx += (long)gridDim.x * 256) {
    int j = (int)(idx & 7);
    int lane = (int)((idx >> 3) & 63);
    long r9 = idx >> 9;
    int ks = (int)(r9 % GRU_KSTEPS);
    long tmp = r9 / GRU_KSTEPS;
    int s = (int)(tmp % 6);
    int blk = (int)(tmp / 6);
    int k = ks * 32 + ((lane >> 4) << 3) + j;
    int u = blk * 16 + (lane & 15);
    float v = 0.f;
    if (s < 3) {
      if (k < 1024) v = w_ih[((long)(s * DD2 + u)) * 1536 + 512 + k];
    } else {
      int nr = (s - 3) * DD2 + u;
      if (k < 1024) v = w_hh[(long)nr * DD2 + k];
      else if (k == 1024) v = b_hh[nr];
    }
    wp[idx] = f2bf(v);
  }
}
__global__ void k_init_hbuf(ushort* hb, unsigned* flags) {
  int i = blockIdx.x * 256 + threadIdx.x;
  if (i < 16384) hb[i] = 0;
  if (i < 1024) flags[i] = 0u;
}

// ---------------------------------------------------------------------------
// Conv GEMM: 64(M)x128(N) tiles, grid (4,128)=512 blocks (2/CU).
// ---------------------------------------------------------------------------
__global__ __launch_bounds__(256) void conv_gemm(
    const ushort* __restrict__ A, const ushort* __restrict__ Bt,
    float* __restrict__ Cout, const float* __restrict__ bias) {
  __shared__ ushort As[64 * 64];    // 8 KB
  __shared__ ushort Bs[128 * 64];   // 16 KB
  const int tid = threadIdx.x, lane = tid & 63, w = tid >> 6;
  const int wr = w >> 1, wc = w & 1;
  const int m0 = blockIdx.y * 64, n0 = blockIdx.x * 128;
  const int b = m0 >> 9, l = m0 & 511;
  const ushort* Abase = A + ((long)(b * LPAD + l)) * DD;
  const ushort* Bbase = Bt + (long)n0 * DD;

  f32x4 acc[2][4];
#pragma unroll
  for (int m = 0; m < 2; m++)
#pragma unroll
    for (int n = 0; n < 4; n++) acc[m][n] = {0.f, 0.f, 0.f, 0.f};

  for (int seg = 0; seg < 9; ++seg) {
    const ushort* Aseg = Abase + (long)seg * DD;
    const ushort* Bseg = Bbase + (long)seg * DD * DD;
    for (int k0 = 0; k0 < DD; k0 += 64) {
#pragma unroll
      for (int it = 0; it < 2; ++it) {
        int chunk = it * 256 + tid;
        int r = chunk >> 3, cc = chunk & 7, sc = cc ^ (r & 7);
        *(short8*)&As[(size_t)chunk * 8] = *(const short8*)(Aseg + (long)r * DD + k0 + sc * 8);
      }
#pragma unroll
      for (int it = 0; it < 4; ++it) {
        int chunk = it * 256 + tid;
        int r = chunk >> 3, cc = chunk & 7, sc = cc ^ (r & 7);
        *(short8*)&Bs[(size_t)chunk * 8] = *(const short8*)(Bseg + (long)r * DD + k0 + sc * 8);
      }
      __syncthreads();
#pragma unroll
      for (int kk = 0; kk < 2; ++kk) {
        short8 af[2], bfv[4];
#pragma unroll
        for (int m = 0; m < 2; m++) {
          int row = wr * 32 + m * 16 + (lane & 15);
          int ch = (kk * 4 + (lane >> 4)) ^ (row & 7);
          af[m] = *(const short8*)&As[(size_t)(row * 8 + ch) * 8];
        }
#pragma unroll
        for (int nn = 0; nn < 4; nn++) {
          int row = wc * 64 + nn * 16 + (lane & 15);
          int ch = (kk * 4 + (lane >> 4)) ^ (row & 7);
          bfv[nn] = *(const short8*)&Bs[(size_t)(row * 8 + ch) * 8];
        }
#pragma unroll
        for (int m = 0; m < 2; m++)
#pragma unroll
          for (int nn = 0; nn < 4; nn++)
            acc[m][nn] = __builtin_amdgcn_mfma_f32_16x16x32_bf16(af[m], bfv[nn], acc[m][nn], 0, 0, 0);
      }
      __syncthreads();
    }
  }
#pragma unroll
  for (int nn = 0; nn < 4; nn++) {
    const int c = n0 + wc * 64 + nn * 16 + (lane & 15);
    const float bv = bias[c];
#pragma unroll
    for (int m = 0; m < 2; m++) {
      const int rbase = m0 + wr * 32 + m * 16 + ((lane >> 4) << 2);
#pragma unroll
      for (int j = 0; j < 4; j++)
        Cout[(long)(rbase + j) * DD + c] = acc[m][nn][j] + bv;
    }
  }
}

// ---------------------------------------------------------------------------
// gi_x GEMM (128x128, packed-gix epilogue) — unchanged.
// ---------------------------------------------------------------------------
__global__ __launch_bounds__(256) void gix_gemm(
    const ushort* __restrict__ A, const ushort* __restrict__ Bt,
    ushort* __restrict__ Cout, const float* __restrict__ bias) {
  __shared__ ushort As[128 * 64];
  __shared__ ushort Bs[128 * 64];
  const int tid = threadIdx.x, lane = tid & 63, w = tid >> 6;
  const int wr = w >> 1, wc = w & 1;
  const int m0 = blockIdx.y * 128, n0 = blockIdx.x * 128;
  const ushort* Abase = A + (long)m0 * DD;
  const ushort* Bbase = Bt + (long)n0 * DD;

  f32x4 acc[4][4];
#pragma unroll
  for (int i = 0; i < 4; i++)
#pragma unroll
    for (int j = 0; j < 4; j++) acc[i][j] = {0.f, 0.f, 0.f, 0.f};

  for (int k0 = 0; k0 < DD; k0 += 64) {
#pragma unroll
    for (int it = 0; it < 4; ++it) {
      int chunk = it * 256 + tid;
      int r = chunk >> 3, cc = chunk & 7, sc = cc ^ (r & 7);
      *(short8*)&As[(size_t)chunk * 8] = *(const short8*)(Abase + (long)r * DD + k0 + sc * 8);
      *(short8*)&Bs[(size_t)chunk * 8] = *(const short8*)(Bbase + (long)r * DD + k0 + sc * 8);
    }
    __syncthreads();
#pragma unroll
    for (int kk = 0; kk < 2; ++kk) {
      short8 af[4], bfv[4];
#pragma unroll
      for (int m = 0; m < 4; m++) {
        int row = wr * 64 + m * 16 + (lane & 15);
        int ch = (kk * 4 + (lane >> 4)) ^ (row & 7);
        af[m] = *(const short8*)&As[(size_t)(row * 8 + ch) * 8];
      }
#pragma unroll
      for (int nn = 0; nn < 4; nn++) {
        int row = wc * 64 + nn * 16 + (lane & 15);
        int ch = (kk * 4 + (lane >> 4)) ^ (row & 7);
        bfv[nn] = *(const short8*)&Bs[(size_t)(row * 8 + ch) * 8];
      }
#pragma unroll
      for (int m = 0; m < 4; m++)
#pragma unroll
        for (int nn = 0; nn < 4; nn++)
          acc[m][nn] = __builtin_amdgcn_mfma_f32_16x16x32_bf16(af[m], bfv[nn], acc[m][nn], 0, 0, 0);
    }
    __syncthreads();
  }
#pragma unroll
  for (int m = 0; m < 4; m++) {
    int rbase = m0 + wr * 64 + m * 16 + ((lane >> 4) << 2);
#pragma unroll
    for (int nn = 0; nn < 4; nn++) {
      int c = n0 + wc * 64 + nn * 16 + (lane & 15);
      const float bv = bias[c];
#pragma unroll
      for (int j = 0; j < 4; j++) {
        float v = acc[m][nn][j] + bv;
        int r = rbase + j;
        int bb = r >> 9, tt = r & 511, ss = c >> 10, uu = c & 1023;
        long o2 = ((((long)(tt * 64 + (uu >> 4))) * 3 + ss) << 8) + (bb << 4) + (uu & 15);
        Cout[o2] = f2bf(v);
      }
    }
  }
}

// ---------------------------------------------------------------------------
// LayerNorm(D=512) + ReLU (unchanged).
// ---------------------------------------------------------------------------
template <int DSTPAD>
__global__ __launch_bounds__(256) void ln_relu(
    const float* __restrict__ y, const float* __restrict__ g,
    const float* __restrict__ be, ushort* __restrict__ dst) {
  const int r = blockIdx.x, tid = threadIdx.x;
  float v0 = y[(long)r * DD + tid];
  float v1 = y[(long)r * DD + 256 + tid];
  float s = v0 + v1, sq = v0 * v0 + v1 * v1;
#pragma unroll
  for (int o = 32; o; o >>= 1) { s += __shfl_down(s, o); sq += __shfl_down(sq, o); }
  __shared__ float red[8];
  int w = tid >> 6, lane = tid & 63;
  if (lane == 0) { red[w] = s; red[4 + w] = sq; }
  __syncthreads();
  if (tid == 0) {
    float ts = 0.f, tq = 0.f;
#pragma unroll
    for (int i = 0; i < 4; i++) { ts += red[i]; tq += red[4 + i]; }
    red[0] = ts; red[1] = tq;
  }
  __syncthreads();
  float mean = red[0] * (1.f / 512.f);
  float var = red[1] * (1.f / 512.f) - mean * mean;
  float rs = rsqrtf(var + 1e-5f);
  long dbase;
  if (DSTPAD) { int b = r >> 9, l = r & 511; dbase = ((long)(b * LPAD + l + 4)) * DD; }
  else dbase = (long)r * DD;
  float o0 = fmaxf(0.f, (v0 - mean) * rs * g[tid] + be[tid]);
  float o1 = fmaxf(0.f, (v1 - mean) * rs * g[tid + 256] + be[tid + 256]);
  dst[dbase + tid] = f2bf(o0);
  dst[dbase + 256 + tid] = f2bf(o1);
}

// ---------------------------------------------------------------------------
// Helpers for the fused kernel. Flags: 4 per block (waves 0-3), one 64B line
// per block. Detect reads each block's line as 2x u64 and checks all 4.
// ---------------------------------------------------------------------------
__device__ __forceinline__ bool line_ok(const unsigned* __restrict__ flags,
                                        int blkline, unsigned need) {
  unsigned long long q0 = __hip_atomic_load(
      (const unsigned long long*)&flags[blkline << 4],
      __ATOMIC_RELAXED, __HIP_MEMORY_SCOPE_AGENT);
  unsigned long long q1 = __hip_atomic_load(
      (const unsigned long long*)&flags[(blkline << 4) + 2],
      __ATOMIC_RELAXED, __HIP_MEMORY_SCOPE_AGENT);
  const unsigned m0 = (unsigned)q0, m1 = (unsigned)(q0 >> 32);
  const unsigned m2 = (unsigned)q1, m3 = (unsigned)(q1 >> 32);
  return (m0 >= need) & (m1 >= need) & (m2 >= need) & (m3 >= need);
}

__device__ __forceinline__ void wait_flags(unsigned need, int tid,
                                           const unsigned* __restrict__ flags) {
  // COARSE polls (r10 lesson: worker poll traffic serializes scan flag lines).
  if ((tid >> 6) == 0) {
    while (1) {
      if (__all((int)line_ok(flags, tid & 63, need))) break;
      __builtin_amdgcn_s_sleep(127);
    }
  }
  __syncthreads();
}

// Paired MDN tile, MR rows (128 or 64) x 128 cols, sigma+mu share the A-tile.
template <int MR>
__device__ void do_pair(int m0, int n0,
                        const ushort* __restrict__ A,
                        const ushort* __restrict__ Bsg, const ushort* __restrict__ Bmu,
                        const float* __restrict__ sg_b, const float* __restrict__ mu_b,
                        float* __restrict__ Cs, float* __restrict__ Cm,
                        char* smem, int tid) {
  constexpr int NF = (MR == 128) ? 2 : 1;   // n-frags per wave
  ushort* As = (ushort*)smem;               // MR*64*2 B
  ushort* B1 = As + MR * 64;                // 16 KB (sigma)
  ushort* B2 = B1 + 128 * 64;               // 16 KB (mu)
  const int lane = tid & 63, w = tid >> 6;
  const int wr = (MR == 128) ? (w >> 2) : 0;
  const int wc = (MR == 128) ? (w & 3) : w;
  const ushort* Abase = A + (long)m0 * DD2;
  const ushort* Bsb = Bsg + (long)n0 * DD2;
  const ushort* Bmb = Bmu + (long)n0 * DD2;
  f32x4 accS[4][NF], accM[4][NF];
#pragma unroll
  for (int m = 0; m < 4; m++)
#pragma unroll
    for (int n = 0; n < NF; n++) { accS[m][n] = {0.f,0.f,0.f,0.f}; accM[m][n] = {0.f,0.f,0.f,0.f}; }

  for (int k0 = 0; k0 < DD2; k0 += 64) {
#pragma unroll
    for (int it = 0; it < MR / 64; ++it) {
      int chunk = it * 512 + tid;
      int r = chunk >> 3, cc = chunk & 7, sc = cc ^ (r & 7);
      *(short8*)&As[(size_t)chunk * 8] = *(const short8*)(Abase + (long)r * DD2 + k0 + sc * 8);
    }
#pragma unroll
    for (int it = 0; it < 2; ++it) {
      int chunk = it * 512 + tid;
      int r = chunk >> 3, cc = chunk & 7, sc = cc ^ (r & 7);
      *(short8*)&B1[(size_t)chunk * 8] = *(const short8*)(Bsb + (long)r * DD2 + k0 + sc * 8);
      *(short8*)&B2[(size_t)chunk * 8] = *(const short8*)(Bmb + (long)r * DD2 + k0 + sc * 8);
    }
    __syncthreads();
#pragma unroll
    for (int kk = 0; kk < 2; ++kk) {
      short8 af[4], b1[NF], b2[NF];
#pragma unroll
      for (int m = 0; m < 4; m++) {
        int row = wr * 64 + m * 16 + (lane & 15);
        int ch = (kk * 4 + (lane >> 4)) ^ (row & 7);
        af[m] = *(const short8*)&As[(size_t)(row * 8 + ch) * 8];
      }
#pragma unroll
      for (int n = 0; n < NF; n++) {
        int row = wc * (16 * NF) + n * 16 + (lane & 15);
        int ch = (kk * 4 + (lane >> 4)) ^ (row & 7);
        b1[n] = *(const short8*)&B1[(size_t)(row * 8 + ch) * 8];
        b2[n] = *(const short8*)&B2[(size_t)(row * 8 + ch) * 8];
      }
#pragma unroll
      for (int m = 0; m < 4; m++)
#pragma unroll
        for (int n = 0; n < NF; n++) {
          accS[m][n] = __builtin_amdgcn_mfma_f32_16x16x32_bf16(af[m], b1[n], accS[m][n], 0, 0, 0);
          accM[m][n] = __builtin_amdgcn_mfma_f32_16x16x32_bf16(af[m], b2[n], accM[m][n], 0, 0, 0);
        }
    }
    __syncthreads();
  }
  const int ldc = KMIX * DD2;  // 8192
#pragma unroll
  for (int n = 0; n < NF; n++) {
    const int c = n0 + wc * (16 * NF) + n * 16 + (lane & 15);
    const float bs = sg_b[c], bm = mu_b[c];
#pragma unroll
    for (int m = 0; m < 4; m++) {
      const int rbase = m0 + wr * 64 + m * 16 + ((lane >> 4) << 2);
#pragma unroll
      for (int j = 0; j < 4; j++) {
        const long off = (long)(rbase + j) * ldc + c;
        Cs[off] = expf(accS[m][n][j] + bs);
        Cm[off] = accM[m][n][j] + bm;
      }
    }
  }
}

// ---------------------------------------------------------------------------
// Fused persistent kernel: 256 blocks x 512 threads, launch_bounds(512,2).
// Scan sync v10: PER-WAVE publish (isolating v6's change (a) from its
// poll-fan-out change (b)): each gate-wave drains ITS OWN h stores with an
// inline vmcnt(0) and raises flags[blk*16+w] — removes the 3rd block-wide
// syncthreads and the tid0 serialization. Detect stays v3: wave0-only poll
// over the 64 padded lines (now checking 4 wave-flags per line), then
// syncthreads broadcast. LDS hazard: a wave passes poll(t+1) only after all
// gate-waves of every block published t+1, which is program-ordered after
// their red[] reads of step t.
// ---------------------------------------------------------------------------
__global__ __launch_bounds__(512, 2) void fused_scan_mdn(
    const ushort* __restrict__ Wp, const ushort* __restrict__ gix2,
    const float* __restrict__ b_hh,
    ushort* __restrict__ hbuf, ushort* __restrict__ h_seq,
    unsigned* __restrict__ flags,
    const ushort* __restrict__ mdnsg, const ushort* __restrict__ mdnmu,
    const float* __restrict__ sg_b, const float* __restrict__ mu_b,
    float* __restrict__ outS, float* __restrict__ outM,
    const float* __restrict__ ww, const float* __restrict__ wb,
    float* __restrict__ outW) {
  __shared__ char smem[49152];
  const int tid = threadIdx.x;

  if (blockIdx.x < 64) {
    // ------------------------- scan role -------------------------
    float* red = (float*)smem;
    const int lane = tid & 63, w = tid >> 6, blk = blockIdx.x;
    const int j_c = w;
    const int u_local = lane & 15;
    const int b = ((lane >> 4) << 2) + (j_c & 3);
    const int u = (blk << 4) + u_local;
    const int lanep = ((blk & 1) * 2 + (u_local >> 3)) * 16 + b;
    const long hout_off = ((long)(blk >> 1) * 64 + lanep) * 8 + (u_local & 7);
    const ushort* wpw = Wp + (long)blk * 6 * GRU_KSTEPS * 512 + (long)lane * 8;
    const float bhr = b_hh[u], bhz = b_hh[DD2 + u], bhn = b_hh[2 * DD2 + u];
    float hold = 0.f;

    short8 wr0[4], wr1[4], wr2[4], wr3[4], wr4[4], wr5[4];
#pragma unroll
    for (int i = 0; i < 4; ++i) {
      const int ks = i * 8 + w;
      wr0[i] = *(const short8*)(wpw + (long)(0 * GRU_KSTEPS + ks) * 512);
      wr1[i] = *(const short8*)(wpw + (long)(1 * GRU_KSTEPS + ks) * 512);
      wr2[i] = *(const short8*)(wpw + (long)(2 * GRU_KSTEPS + ks) * 512);
      wr3[i] = *(const short8*)(wpw + (long)(3 * GRU_KSTEPS + ks) * 512);
      wr4[i] = *(const short8*)(wpw + (long)(4 * GRU_KSTEPS + ks) * 512);
      wr5[i] = *(const short8*)(wpw + (long)(5 * GRU_KSTEPS + ks) * 512);
    }

    const int gofs = (b << 4) + u_local;
    for (int t = 0; t < LL; ++t) {
      float gx_r = 0.f, gx_z = 0.f, gx_n = 0.f;
      if (w < 4) {
        const long gbase = ((long)(t * 64 + blk) * 3) << 8;
        gx_r = bf2f(__builtin_nontemporal_load(gix2 + gbase + gofs));
        gx_z = bf2f(__builtin_nontemporal_load(gix2 + gbase + 256 + gofs));
        gx_n = bf2f(__builtin_nontemporal_load(gix2 + gbase + 512 + gofs));
      }
      if (t > 0) {
        if (w == 0) {
          const unsigned tgt = (unsigned)t;
          while (1) {
            if (__all((int)line_ok(flags, lane, tgt))) break;
            __builtin_amdgcn_s_sleep(1);
          }
        }
        __syncthreads();
      }

      const ushort* hb = hbuf + ((long)t << 14);
      f32x4 acc0 = {0.f,0.f,0.f,0.f}, acc1 = acc0, acc2 = acc0,
            acc3 = acc0, acc4 = acc0, acc5 = acc0;
#pragma unroll
      for (int i = 0; i < 4; ++i) {
        const int ks = i * 8 + w;
        unsigned long long* ap = (unsigned long long*)(hb + (((long)ks * 64 + lane) << 3));
        union { unsigned long long q[2]; short8 v; } cv;
        cv.q[0] = __hip_atomic_load(ap,     __ATOMIC_RELAXED, __HIP_MEMORY_SCOPE_AGENT);
        cv.q[1] = __hip_atomic_load(ap + 1, __ATOMIC_RELAXED, __HIP_MEMORY_SCOPE_AGENT);
        acc0 = __builtin_amdgcn_mfma_f32_16x16x32_bf16(cv.v, wr0[i], acc0, 0, 0, 0);
        acc1 = __builtin_amdgcn_mfma_f32_16x16x32_bf16(cv.v, wr1[i], acc1, 0, 0, 0);
        acc2 = __builtin_amdgcn_mfma_f32_16x16x32_bf16(cv.v, wr2[i], acc2, 0, 0, 0);
        acc3 = __builtin_amdgcn_mfma_f32_16x16x32_bf16(cv.v, wr3[i], acc3, 0, 0, 0);
        acc4 = __builtin_amdgcn_mfma_f32_16x16x32_bf16(cv.v, wr4[i], acc4, 0, 0, 0);
        acc5 = __builtin_amdgcn_mfma_f32_16x16x32_bf16(cv.v, wr5[i], acc5, 0, 0, 0);
      }
#pragma unroll
      for (int j = 0; j < 4; ++j) {
        red[((w * 6 + 0) << 8) + (j << 6) + lane] = acc0[j];
        red[((w * 6 + 1) << 8) + (j << 6) + lane] = acc1[j];
        red[((w * 6 + 2) << 8) + (j << 6) + lane] = acc2[j];
        red[((w * 6 + 3) << 8) + (j << 6) + lane] = acc3[j];
        red[((w * 6 + 4) << 8) + (j << 6) + lane] = acc4[j];
        red[((w * 6 + 5) << 8) + (j << 6) + lane] = acc5[j];
      }
      __syncthreads();
      if (w < 4) {
        float v0 = 0.f, v1 = 0.f, v2 = 0.f, v3 = 0.f, v4 = 0.f, v5 = 0.f;
#pragma unroll
        for (int wv = 0; wv < 8; ++wv) {
          const int base = ((wv * 6) << 8) + (j_c << 6) + lane;
          v0 += red[base];
          v1 += red[base + 256];
          v2 += red[base + 512];
          v3 += red[base + 768];
          v4 += red[base + 1024];
          v5 += red[base + 1280];
        }
        const float rg = 1.f / (1.f + __expf(-(gx_r + v0 + v3 + bhr)));
        const float zg = 1.f / (1.f + __expf(-(gx_z + v1 + v4 + bhz)));
        const float nx = gx_n + v2 + rg * (v5 + bhn);
        const float ng = 1.f - 2.f / (__expf(2.f * nx) + 1.f);
        const float hn = (1.f - zg) * ng + zg * hold;
        hold = hn;
        const ushort h16 = f2bf(hn);
        if (t < LL - 1) {
          // publish h, drain THIS WAVE's stores, raise this wave's flag.
          __hip_atomic_store(hbuf + (((long)(t + 1)) << 14) + hout_off, h16,
                             __ATOMIC_RELAXED, __HIP_MEMORY_SCOPE_AGENT);
          asm volatile("s_waitcnt vmcnt(0)" ::: "memory");
          if (lane == 0)
            __hip_atomic_store(&flags[(blk << 4) + w], (unsigned)(t + 1),
                               __ATOMIC_RELAXED, __HIP_MEMORY_SCOPE_AGENT);
        }
        // h_seq publish: agent-atomic, issued after the flag (off critical
        // path; drained by this wave's vmcnt before flag t+2).
        __hip_atomic_store(h_seq + ((long)b * LL + t) * DD2 + u, h16,
                           __ATOMIC_RELAXED, __HIP_MEMORY_SCOPE_AGENT);
      }
    }
    // Final publish: each gate-wave drains (covers h_seq[510..511]) then 600.
    if (w < 4) {
      asm volatile("s_waitcnt vmcnt(0)" ::: "memory");
      if (lane == 0)
        __hip_atomic_store(&flags[(blk << 4) + w], 600u, __ATOMIC_RELAXED,
                           __HIP_MEMORY_SCOPE_AGENT);
    }
  } else {
    // ------------------------- worker role -------------------------
    const int wid = blockIdx.x - 64;
    // main pairs: t0 in {0,128,256}
    for (int i = wid; i < 3072; i += 192) {
      const int nb = i & 63;
      const int rest = i >> 6;
      const int b = rest & 15;
      const int t0 = (rest >> 4) * 128;
      wait_flags((unsigned)(t0 + 129), tid, flags);
      do_pair<128>(b * 512 + t0, nb * 128, h_seq, mdnsg, mdnmu, sg_b, mu_b,
                   outS, outM, smem, tid);
    }
    // late pairs: rows 384..447 (MR=64), gated mid-scan at flag 449
    for (int i = wid; i < 1024; i += 192) {
      const int nb = i & 63;
      const int b = (i >> 6) & 15;
      wait_flags(449u, tid, flags);
      do_pair<64>(b * 512 + 384, nb * 128, h_seq, mdnsg, mdnmu, sg_b, mu_b,
                  outS, outM, smem, tid);
    }
  }
  // ------------------------- tail (all 256 blocks): rows 448..511 ----------
  for (int i = blockIdx.x; i < 1024; i += 256) {
    const int nb = i & 63;
    const int b = (i >> 6) & 15;
    wait_flags(513u, tid, flags);
    do_pair<64>(b * 512 + 448, nb * 128, h_seq, mdnsg, mdnmu, sg_b, mu_b,
                outS, outM, smem, tid);
  }
  // ------------------------- w_head fold (all 256 blocks) ------------------
  // (flag >= 513 already established by the tail loop's gates.)
  {
    const int lane = tid & 63, w = tid >> 6;
#pragma unroll
    for (int i = 0; i < 4; ++i) {
      const long r = (long)blockIdx.x * 32 + i * 8 + w;
      float s[KMIX];
#pragma unroll
      for (int k = 0; k < KMIX; k++) s[k] = 0.f;
      for (int u = lane; u < DD2; u += 64) {
        float hv = bf2f(h_seq[r * DD2 + u]);
#pragma unroll
        for (int k = 0; k < KMIX; k++) s[k] += hv * ww[(long)k * DD2 + u];
      }
#pragma unroll
      for (int k = 0; k < KMIX; k++)
#pragma unroll
        for (int o = 32; o; o >>= 1) s[k] += __shfl_xor(s[k], o);
#pragma unroll
      for (int k = 0; k < KMIX; k++) s[k] += wb[k];
      float m = s[0];
#pragma unroll
      for (int k = 1; k < KMIX; k++) m = fmaxf(m, s[k]);
      float esum = 0.f;
#pragma unroll
      for (int k = 0; k < KMIX; k++) { s[k] = expf(s[k] - m); esum += s[k]; }
      float mine = 0.f;
#pragma unroll
      for (int k = 0; k < KMIX; k++) if (lane == k) mine = s[k];
      if (lane < KMIX) outW[r * KMIX + lane] = mine / esum;
    }
  }
}

// ---------------------------------------------------------------------------
extern "C" void kernel_launch(void* const* d_in, const int* in_sizes, int n_in,
                              void* d_out, int out_size, void* d_ws, size_t ws_size,
                              hipStream_t stream) {
  const float* h_text     = (const float*)d_in[0];
  const float* conv1_w    = (const float*)d_in[1];
  const float* conv1_b    = (const float*)d_in[2];
  const float* ln1_g      = (const float*)d_in[3];
  const float* ln1_b      = (const float*)d_in[4];
  const float* conv2_w    = (const float*)d_in[5];
  const float* conv2_b    = (const float*)d_in[6];
  const float* ln2_g      = (const float*)d_in[7];
  const float* ln2_b      = (const float*)d_in[8];
  const float* w_ih       = (const float*)d_in[9];
  const float* w_hh       = (const float*)d_in[10];
  const float* b_ih       = (const float*)d_in[11];
  const float* b_hh       = (const float*)d_in[12];
  const float* mdn_w_w    = (const float*)d_in[13];
  const float* mdn_w_b    = (const float*)d_in[14];
  const float* mdn_sig_w  = (const float*)d_in[15];
  const float* mdn_sig_b  = (const float*)d_in[16];
  const float* mdn_mu_w   = (const float*)d_in[17];
  const float* mdn_mu_b   = (const float*)d_in[18];
  float* out = (float*)d_out;

  char* ws = (char*)d_ws;
  size_t off = 0;
  auto take = [&](size_t bytes) {
    void* p = ws + off;
    off += (bytes + 255) & ~(size_t)255;
    return p;
  };
  ushort* xpad1  = (ushort*)take((size_t)BB * LPAD * DD * 2);
  ushort* xpad2  = (ushort*)take((size_t)BB * LPAD * DD * 2);
  ushort* wpack1 = (ushort*)take((size_t)DD * DD * 9 * 2);
  ushort* wpack2 = (ushort*)take((size_t)DD * DD * 9 * 2);
  float*  ybuf   = (float*) take((size_t)BB * LL * DD * 4);
  ushort* x2     = (ushort*)take((size_t)BB * LL * DD * 2);
  ushort* wihx   = (ushort*)take((size_t)3 * DD2 * DD * 2);
  ushort* gix    = (ushort*)take((size_t)BB * LL * 3 * DD2 * 2);   // packed layout
  ushort* Wp     = (ushort*)take((size_t)64 * 6 * GRU_KSTEPS * 64 * 8 * 2);
  ushort* hseq   = (ushort*)take((size_t)BB * LL * DD2 * 2);
  ushort* mdnmu  = (ushort*)take((size_t)KMIX * DD2 * DD2 * 2);
  ushort* mdnsg  = (ushort*)take((size_t)KMIX * DD2 * DD2 * 2);
  ushort* hbuf   = (ushort*)take((size_t)512 * 16384 * 2);   // 512 write-once frag buffers
  unsigned* flags = (unsigned*)take(64 * 16 * 4);            // 64 lines x 4 wave-flags

  const long sigma_off = (long)BB * LL * KMIX;                    // 65536
  const long mu_off    = sigma_off + (long)BB * LL * KMIX * DD2;  // 67174400

  // --- prep / packing ---
  k_fill_xpad<<<2048, 256, 0, stream>>>(h_text, xpad1);
  k_zero_bf16<<<2048, 256, 0, stream>>>(xpad2, (long)BB * LPAD * DD);
  k_pack_convw<<<2048, 256, 0, stream>>>(conv1_w, wpack1);
  k_pack_convw<<<2048, 256, 0, stream>>>(conv2_w, wpack2);
  k_pack_wihx<<<2048, 256, 0, stream>>>(w_ih, wihx);
  k_pack_gru<<<2048, 256, 0, stream>>>(w_ih, w_hh, b_hh, Wp);
  k_pack_bf16<<<2048, 256, 0, stream>>>(mdn_mu_w, mdnmu, (long)KMIX * DD2 * DD2);
  k_pack_bf16<<<2048, 256, 0, stream>>>(mdn_sig_w, mdnsg, (long)KMIX * DD2 * DD2);
  k_init_hbuf<<<64, 256, 0, stream>>>(hbuf, flags);

  // --- conv block 1: y = conv(xpad1) + b ; LN+ReLU -> xpad2 ---
  conv_gemm<<<dim3(4, 128), 256, 0, stream>>>(xpad1, wpack1, ybuf, conv1_b);
  ln_relu<1><<<BB * LL, 256, 0, stream>>>(ybuf, ln1_g, ln1_b, xpad2);

  // --- conv block 2 -> x2 (GRU input, plain bf16 [8192,512]) ---
  conv_gemm<<<dim3(4, 128), 256, 0, stream>>>(xpad2, wpack2, ybuf, conv2_b);
  ln_relu<0><<<BB * LL, 256, 0, stream>>>(ybuf, ln2_g, ln2_b, x2);

  // --- gi_x = x2 @ w_ih[:, :512]^T + b_ih -> PACKED gix layout ---
  gix_gemm<<<dim3(24, 64), 256, 0, stream>>>(x2, wihx, gix, b_ih);

  // --- fused persistent scan + MDN heads + w_head (single dispatch) ---
  fused_scan_mdn<<<256, 512, 0, stream>>>(Wp, gix, b_hh, hbuf, hseq, flags,
                                          mdnsg, mdnmu, mdn_sig_b, mdn_mu_b,
                                          out + sigma_off, out + mu_off,
                                          mdn_w_w, mdn_w_b, out);
}

// Round 14
// 1702.579 us; speedup vs baseline: 1.2691x; 1.2691x over previous
//
#include <hip/hip_runtime.h>
#include <hip/hip_bf16.h>
#include <math.h>

// Problem constants
#define BB 16
#define LL 512
#define DD 512
#define DD2 1024
#define KMIX 8
#define LPAD 520          // L + 8 pad rows (4 each side) for KS=9 conv
#define GRU_KSTEPS 33     // Wp layout keeps 33 k-steps; scan uses 0..31 (bias via scalars)

typedef __attribute__((ext_vector_type(8))) short short8;
typedef __attribute__((ext_vector_type(4))) float f32x4;
typedef unsigned short ushort;

__device__ __forceinline__ float bf2f(ushort u) {
  union { float f; unsigned i; } v; v.i = ((unsigned)u) << 16; return v.f;
}
__device__ __forceinline__ ushort f2bf(float f) {
  union { float f; unsigned i; } v; v.f = f;
  unsigned i = v.i;
  unsigned r = i + 0x7FFF + ((i >> 16) & 1);   // RNE
  return (ushort)(r >> 16);
}

// ---------------------------------------------------------------------------
// Mega prep: all 9 elementwise prep tasks in ONE dispatch, partitioned by
// blockIdx range (each task grid-strides within its partition). Saves ~8
// launch gaps vs separate kernels; all tasks are independent.
// ---------------------------------------------------------------------------
__global__ __launch_bounds__(256) void mega_prep(
    const float* __restrict__ x, ushort* __restrict__ xpad1, ushort* __restrict__ xpad2,
    const float* __restrict__ conv1_w, ushort* __restrict__ wpack1,
    const float* __restrict__ conv2_w, ushort* __restrict__ wpack2,
    const float* __restrict__ w_ih, ushort* __restrict__ wihx,
    const float* __restrict__ w_hh, const float* __restrict__ b_hh, ushort* __restrict__ Wp,
    const float* __restrict__ mdn_mu_w, ushort* __restrict__ mdnmu,
    const float* __restrict__ mdn_sig_w, ushort* __restrict__ mdnsg,
    ushort* __restrict__ hbuf, unsigned* __restrict__ flags) {
  const int blk = blockIdx.x, tid = threadIdx.x;
  if (blk < 256) {
    // xpad1[b][p][d] = p in [4,516) ? bf16(x[b][p-4][d]) : 0
    const long n = (long)BB * LPAD * DD;
    for (long i = (long)blk * 256 + tid; i < n; i += 256L * 256) {
      int d = (int)(i & 511);
      long rest = i >> 9;
      int p = (int)(rest % LPAD);
      int b = (int)(rest / LPAD);
      float v = 0.f;
      if (p >= 4 && p < 516) v = x[((long)b * LL + (p - 4)) * DD + d];
      xpad1[i] = f2bf(v);
    }
  } else if (blk < 512) {
    const long n = (long)BB * LPAD * DD;
    for (long i = (long)(blk - 256) * 256 + tid; i < n; i += 256L * 256) xpad2[i] = 0;
  } else if (blk < 640) {
    // wpack1[k][o][i] = conv1_w[o][i][k]
    const long n = (long)DD * DD * 9;
    for (long idx = (long)(blk - 512) * 256 + tid; idx < n; idx += 128L * 256) {
      int i = (int)(idx & 511);
      int o = (int)((idx >> 9) & 511);
      int k = (int)(idx >> 18);
      wpack1[idx] = f2bf(conv1_w[((long)o * DD + i) * 9 + k]);
    }
  } else if (blk < 768) {
    const long n = (long)DD * DD * 9;
    for (long idx = (long)(blk - 640) * 256 + tid; idx < n; idx += 128L * 256) {
      int i = (int)(idx & 511);
      int o = (int)((idx >> 9) & 511);
      int k = (int)(idx >> 18);
      wpack2[idx] = f2bf(conv2_w[((long)o * DD + i) * 9 + k]);
    }
  } else if (blk < 832) {
    // wihx[n][i] = w_ih[n][i], n<3072, i<512
    const long n = (long)3 * DD2 * DD;
    for (long idx = (long)(blk - 768) * 256 + tid; idx < n; idx += 64L * 256) {
      int i = (int)(idx & 511);
      int nr = (int)(idx >> 9);
      wihx[idx] = f2bf(w_ih[(long)nr * 1536 + i]);
    }
  } else if (blk < 1088) {
    // GRU weights in exact B-fragment order.
    const long n = (long)64 * 6 * GRU_KSTEPS * 64 * 8;
    for (long idx = (long)(blk - 832) * 256 + tid; idx < n; idx += 256L * 256) {
      int j = (int)(idx & 7);
      int lane = (int)((idx >> 3) & 63);
      long r9 = idx >> 9;
      int ks = (int)(r9 % GRU_KSTEPS);
      long tmp = r9 / GRU_KSTEPS;
      int s = (int)(tmp % 6);
      int bq = (int)(tmp / 6);
      int k = ks * 32 + ((lane >> 4) << 3) + j;
      int u = bq * 16 + (lane & 15);
      float v = 0.f;
      if (s < 3) {
        if (k < 1024) v = w_ih[((long)(s * DD2 + u)) * 1536 + 512 + k];
      } else {
        int nr = (s - 3) * DD2 + u;
        if (k < 1024) v = w_hh[(long)nr * DD2 + k];
        else if (k == 1024) v = b_hh[nr];
      }
      Wp[idx] = f2bf(v);
    }
  } else if (blk < 1560) {
    const long n = (long)KMIX * DD2 * DD2;
    for (long i = (long)(blk - 1088) * 256 + tid; i < n; i += 472L * 256)
      mdnmu[i] = f2bf(mdn_mu_w[i]);
  } else if (blk < 2032) {
    const long n = (long)KMIX * DD2 * DD2;
    for (long i = (long)(blk - 1560) * 256 + tid; i < n; i += 472L * 256)
      mdnsg[i] = f2bf(mdn_sig_w[i]);
  } else {
    // init hbuf[0] (h0=0 frag order) + flags
    for (int i = (blk - 2032) * 256 + tid; i < 16384; i += 16 * 256) hbuf[i] = 0;
    for (int i = (blk - 2032) * 256 + tid; i < 1024; i += 16 * 256) flags[i] = 0u;
  }
}

// ---------------------------------------------------------------------------
// Conv GEMM: 64(M)x128(N) tiles, grid (4,128)=512 blocks (2/CU).
// ---------------------------------------------------------------------------
__global__ __launch_bounds__(256) void conv_gemm(
    const ushort* __restrict__ A, const ushort* __restrict__ Bt,
    float* __restrict__ Cout, const float* __restrict__ bias) {
  __shared__ ushort As[64 * 64];    // 8 KB
  __shared__ ushort Bs[128 * 64];   // 16 KB
  const int tid = threadIdx.x, lane = tid & 63, w = tid >> 6;
  const int wr = w >> 1, wc = w & 1;
  const int m0 = blockIdx.y * 64, n0 = blockIdx.x * 128;
  const int b = m0 >> 9, l = m0 & 511;
  const ushort* Abase = A + ((long)(b * LPAD + l)) * DD;
  const ushort* Bbase = Bt + (long)n0 * DD;

  f32x4 acc[2][4];
#pragma unroll
  for (int m = 0; m < 2; m++)
#pragma unroll
    for (int n = 0; n < 4; n++) acc[m][n] = {0.f, 0.f, 0.f, 0.f};

  for (int seg = 0; seg < 9; ++seg) {
    const ushort* Aseg = Abase + (long)seg * DD;
    const ushort* Bseg = Bbase + (long)seg * DD * DD;
    for (int k0 = 0; k0 < DD; k0 += 64) {
#pragma unroll
      for (int it = 0; it < 2; ++it) {
        int chunk = it * 256 + tid;
        int r = chunk >> 3, cc = chunk & 7, sc = cc ^ (r & 7);
        *(short8*)&As[(size_t)chunk * 8] = *(const short8*)(Aseg + (long)r * DD + k0 + sc * 8);
      }
#pragma unroll
      for (int it = 0; it < 4; ++it) {
        int chunk = it * 256 + tid;
        int r = chunk >> 3, cc = chunk & 7, sc = cc ^ (r & 7);
        *(short8*)&Bs[(size_t)chunk * 8] = *(const short8*)(Bseg + (long)r * DD + k0 + sc * 8);
      }
      __syncthreads();
#pragma unroll
      for (int kk = 0; kk < 2; ++kk) {
        short8 af[2], bfv[4];
#pragma unroll
        for (int m = 0; m < 2; m++) {
          int row = wr * 32 + m * 16 + (lane & 15);
          int ch = (kk * 4 + (lane >> 4)) ^ (row & 7);
          af[m] = *(const short8*)&As[(size_t)(row * 8 + ch) * 8];
        }
#pragma unroll
        for (int nn = 0; nn < 4; nn++) {
          int row = wc * 64 + nn * 16 + (lane & 15);
          int ch = (kk * 4 + (lane >> 4)) ^ (row & 7);
          bfv[nn] = *(const short8*)&Bs[(size_t)(row * 8 + ch) * 8];
        }
#pragma unroll
        for (int m = 0; m < 2; m++)
#pragma unroll
          for (int nn = 0; nn < 4; nn++)
            acc[m][nn] = __builtin_amdgcn_mfma_f32_16x16x32_bf16(af[m], bfv[nn], acc[m][nn], 0, 0, 0);
      }
      __syncthreads();
    }
  }
#pragma unroll
  for (int nn = 0; nn < 4; nn++) {
    const int c = n0 + wc * 64 + nn * 16 + (lane & 15);
    const float bv = bias[c];
#pragma unroll
    for (int m = 0; m < 2; m++) {
      const int rbase = m0 + wr * 32 + m * 16 + ((lane >> 4) << 2);
#pragma unroll
      for (int j = 0; j < 4; j++)
        Cout[(long)(rbase + j) * DD + c] = acc[m][nn][j] + bv;
    }
  }
}

// ---------------------------------------------------------------------------
// gi_x GEMM (128x128, packed-gix epilogue).
// ---------------------------------------------------------------------------
__global__ __launch_bounds__(256) void gix_gemm(
    const ushort* __restrict__ A, const ushort* __restrict__ Bt,
    ushort* __restrict__ Cout, const float* __restrict__ bias) {
  __shared__ ushort As[128 * 64];
  __shared__ ushort Bs[128 * 64];
  const int tid = threadIdx.x, lane = tid & 63, w = tid >> 6;
  const int wr = w >> 1, wc = w & 1;
  const int m0 = blockIdx.y * 128, n0 = blockIdx.x * 128;
  const ushort* Abase = A + (long)m0 * DD;
  const ushort* Bbase = Bt + (long)n0 * DD;

  f32x4 acc[4][4];
#pragma unroll
  for (int i = 0; i < 4; i++)
#pragma unroll
    for (int j = 0; j < 4; j++) acc[i][j] = {0.f, 0.f, 0.f, 0.f};

  for (int k0 = 0; k0 < DD; k0 += 64) {
#pragma unroll
    for (int it = 0; it < 4; ++it) {
      int chunk = it * 256 + tid;
      int r = chunk >> 3, cc = chunk & 7, sc = cc ^ (r & 7);
      *(short8*)&As[(size_t)chunk * 8] = *(const short8*)(Abase + (long)r * DD + k0 + sc * 8);
      *(short8*)&Bs[(size_t)chunk * 8] = *(const short8*)(Bbase + (long)r * DD + k0 + sc * 8);
    }
    __syncthreads();
#pragma unroll
    for (int kk = 0; kk < 2; ++kk) {
      short8 af[4], bfv[4];
#pragma unroll
      for (int m = 0; m < 4; m++) {
        int row = wr * 64 + m * 16 + (lane & 15);
        int ch = (kk * 4 + (lane >> 4)) ^ (row & 7);
        af[m] = *(const short8*)&As[(size_t)(row * 8 + ch) * 8];
      }
#pragma unroll
      for (int nn = 0; nn < 4; nn++) {
        int row = wc * 64 + nn * 16 + (lane & 15);
        int ch = (kk * 4 + (lane >> 4)) ^ (row & 7);
        bfv[nn] = *(const short8*)&Bs[(size_t)(row * 8 + ch) * 8];
      }
#pragma unroll
      for (int m = 0; m < 4; m++)
#pragma unroll
        for (int nn = 0; nn < 4; nn++)
          acc[m][nn] = __builtin_amdgcn_mfma_f32_16x16x32_bf16(af[m], bfv[nn], acc[m][nn], 0, 0, 0);
    }
    __syncthreads();
  }
#pragma unroll
  for (int m = 0; m < 4; m++) {
    int rbase = m0 + wr * 64 + m * 16 + ((lane >> 4) << 2);
#pragma unroll
    for (int nn = 0; nn < 4; nn++) {
      int c = n0 + wc * 64 + nn * 16 + (lane & 15);
      const float bv = bias[c];
#pragma unroll
      for (int j = 0; j < 4; j++) {
        float v = acc[m][nn][j] + bv;
        int r = rbase + j;
        int bb = r >> 9, tt = r & 511, ss = c >> 10, uu = c & 1023;
        long o2 = ((((long)(tt * 64 + (uu >> 4))) * 3 + ss) << 8) + (bb << 4) + (uu & 15);
        Cout[o2] = f2bf(v);
      }
    }
  }
}

// ---------------------------------------------------------------------------
// LayerNorm(D=512) + ReLU.
// ---------------------------------------------------------------------------
template <int DSTPAD>
__global__ __launch_bounds__(256) void ln_relu(
    const float* __restrict__ y, const float* __restrict__ g,
    const float* __restrict__ be, ushort* __restrict__ dst) {
  const int r = blockIdx.x, tid = threadIdx.x;
  float v0 = y[(long)r * DD + tid];
  float v1 = y[(long)r * DD + 256 + tid];
  float s = v0 + v1, sq = v0 * v0 + v1 * v1;
#pragma unroll
  for (int o = 32; o; o >>= 1) { s += __shfl_down(s, o); sq += __shfl_down(sq, o); }
  __shared__ float red[8];
  int w = tid >> 6, lane = tid & 63;
  if (lane == 0) { red[w] = s; red[4 + w] = sq; }
  __syncthreads();
  if (tid == 0) {
    float ts = 0.f, tq = 0.f;
#pragma unroll
    for (int i = 0; i < 4; i++) { ts += red[i]; tq += red[4 + i]; }
    red[0] = ts; red[1] = tq;
  }
  __syncthreads();
  float mean = red[0] * (1.f / 512.f);
  float var = red[1] * (1.f / 512.f) - mean * mean;
  float rs = rsqrtf(var + 1e-5f);
  long dbase;
  if (DSTPAD) { int b = r >> 9, l = r & 511; dbase = ((long)(b * LPAD + l + 4)) * DD; }
  else dbase = (long)r * DD;
  float o0 = fmaxf(0.f, (v0 - mean) * rs * g[tid] + be[tid]);
  float o1 = fmaxf(0.f, (v1 - mean) * rs * g[tid + 256] + be[tid + 256]);
  dst[dbase + tid] = f2bf(o0);
  dst[dbase + 256 + tid] = f2bf(o1);
}

// ---------------------------------------------------------------------------
// Helpers for the fused kernel (r12-validated structure).
// ---------------------------------------------------------------------------
__device__ __forceinline__ void wait_flags(unsigned need, int tid,
                                           const unsigned* __restrict__ flags) {
  // COARSE polls (r10 lesson: worker poll traffic serializes scan flag lines).
  if ((tid >> 6) == 0) {
    while (1) {
      unsigned f = __hip_atomic_load(&flags[(tid & 63) << 4], __ATOMIC_RELAXED,
                                     __HIP_MEMORY_SCOPE_AGENT);
      if (__all((int)(f >= need))) break;
      __builtin_amdgcn_s_sleep(127);
    }
  }
  __syncthreads();
}

// Paired MDN tile, MR rows (128 or 64) x 128 cols, sigma+mu share the A-tile.
template <int MR>
__device__ void do_pair(int m0, int n0,
                        const ushort* __restrict__ A,
                        const ushort* __restrict__ Bsg, const ushort* __restrict__ Bmu,
                        const float* __restrict__ sg_b, const float* __restrict__ mu_b,
                        float* __restrict__ Cs, float* __restrict__ Cm,
                        char* smem, int tid) {
  constexpr int NF = (MR == 128) ? 2 : 1;   // n-frags per wave
  ushort* As = (ushort*)smem;               // MR*64*2 B
  ushort* B1 = As + MR * 64;                // 16 KB (sigma)
  ushort* B2 = B1 + 128 * 64;               // 16 KB (mu)
  const int lane = tid & 63, w = tid >> 6;
  const int wr = (MR == 128) ? (w >> 2) : 0;
  const int wc = (MR == 128) ? (w & 3) : w;
  const ushort* Abase = A + (long)m0 * DD2;
  const ushort* Bsb = Bsg + (long)n0 * DD2;
  const ushort* Bmb = Bmu + (long)n0 * DD2;
  f32x4 accS[4][NF], accM[4][NF];
#pragma unroll
  for (int m = 0; m < 4; m++)
#pragma unroll
    for (int n = 0; n < NF; n++) { accS[m][n] = {0.f,0.f,0.f,0.f}; accM[m][n] = {0.f,0.f,0.f,0.f}; }

  for (int k0 = 0; k0 < DD2; k0 += 64) {
#pragma unroll
    for (int it = 0; it < MR / 64; ++it) {
      int chunk = it * 512 + tid;
      int r = chunk >> 3, cc = chunk & 7, sc = cc ^ (r & 7);
      *(short8*)&As[(size_t)chunk * 8] = *(const short8*)(Abase + (long)r * DD2 + k0 + sc * 8);
    }
#pragma unroll
    for (int it = 0; it < 2; ++it) {
      int chunk = it * 512 + tid;
      int r = chunk >> 3, cc = chunk & 7, sc = cc ^ (r & 7);
      *(short8*)&B1[(size_t)chunk * 8] = *(const short8*)(Bsb + (long)r * DD2 + k0 + sc * 8);
      *(short8*)&B2[(size_t)chunk * 8] = *(const short8*)(Bmb + (long)r * DD2 + k0 + sc * 8);
    }
    __syncthreads();
#pragma unroll
    for (int kk = 0; kk < 2; ++kk) {
      short8 af[4], b1[NF], b2[NF];
#pragma unroll
      for (int m = 0; m < 4; m++) {
        int row = wr * 64 + m * 16 + (lane & 15);
        int ch = (kk * 4 + (lane >> 4)) ^ (row & 7);
        af[m] = *(const short8*)&As[(size_t)(row * 8 + ch) * 8];
      }
#pragma unroll
      for (int n = 0; n < NF; n++) {
        int row = wc * (16 * NF) + n * 16 + (lane & 15);
        int ch = (kk * 4 + (lane >> 4)) ^ (row & 7);
        b1[n] = *(const short8*)&B1[(size_t)(row * 8 + ch) * 8];
        b2[n] = *(const short8*)&B2[(size_t)(row * 8 + ch) * 8];
      }
#pragma unroll
      for (int m = 0; m < 4; m++)
#pragma unroll
        for (int n = 0; n < NF; n++) {
          accS[m][n] = __builtin_amdgcn_mfma_f32_16x16x32_bf16(af[m], b1[n], accS[m][n], 0, 0, 0);
          accM[m][n] = __builtin_amdgcn_mfma_f32_16x16x32_bf16(af[m], b2[n], accM[m][n], 0, 0, 0);
        }
    }
    __syncthreads();
  }
  const int ldc = KMIX * DD2;  // 8192
#pragma unroll
  for (int n = 0; n < NF; n++) {
    const int c = n0 + wc * (16 * NF) + n * 16 + (lane & 15);
    const float bs = sg_b[c], bm = mu_b[c];
#pragma unroll
    for (int m = 0; m < 4; m++) {
      const int rbase = m0 + wr * 64 + m * 16 + ((lane >> 4) << 2);
#pragma unroll
      for (int j = 0; j < 4; j++) {
        const long off = (long)(rbase + j) * ldc + c;
        Cs[off] = expf(accS[m][n][j] + bs);
        Cm[off] = accM[m][n][j] + bm;
      }
    }
  }
}

// ---------------------------------------------------------------------------
// Fused persistent kernel: 256 blocks x 512 threads, launch_bounds(512,2).
// SYNC SKELETON = r12 (v3-family, CONVERGED after 5 failed deviations):
//   publish: all gate-waves store h (relaxed agent), block-wide __syncthreads
//            (vmcnt drain), tid0 raises the block's SINGLE flag.
//   detect:  wave0-only poll of the 64 padded flag lines, then syncthreads.
//   blocks 0-63: scan; blocks 64-255: MDN workers (main MR128 gates t0+129,
//   late MR64 gate 449); tail MR64 gate 513 on all blocks; w_head folded.
// ---------------------------------------------------------------------------
__global__ __launch_bounds__(512, 2) void fused_scan_mdn(
    const ushort* __restrict__ Wp, const ushort* __restrict__ gix2,
    const float* __restrict__ b_hh,
    ushort* __restrict__ hbuf, ushort* __restrict__ h_seq,
    unsigned* __restrict__ flags,
    const ushort* __restrict__ mdnsg, const ushort* __restrict__ mdnmu,
    const float* __restrict__ sg_b, const float* __restrict__ mu_b,
    float* __restrict__ outS, float* __restrict__ outM,
    const float* __restrict__ ww, const float* __restrict__ wb,
    float* __restrict__ outW) {
  __shared__ char smem[49152];
  const int tid = threadIdx.x;

  if (blockIdx.x < 64) {
    // ------------------------- scan role (v9/r12) -------------------------
    float* red = (float*)smem;
    const int lane = tid & 63, w = tid >> 6, blk = blockIdx.x;
    const int j_c = w;
    const int u_local = lane & 15;
    const int b = ((lane >> 4) << 2) + (j_c & 3);
    const int u = (blk << 4) + u_local;
    const int lanep = ((blk & 1) * 2 + (u_local >> 3)) * 16 + b;
    const long hout_off = ((long)(blk >> 1) * 64 + lanep) * 8 + (u_local & 7);
    const ushort* wpw = Wp + (long)blk * 6 * GRU_KSTEPS * 512 + (long)lane * 8;
    const float bhr = b_hh[u], bhz = b_hh[DD2 + u], bhn = b_hh[2 * DD2 + u];
    float hold = 0.f;

    short8 wr0[4], wr1[4], wr2[4], wr3[4], wr4[4], wr5[4];
#pragma unroll
    for (int i = 0; i < 4; ++i) {
      const int ks = i * 8 + w;
      wr0[i] = *(const short8*)(wpw + (long)(0 * GRU_KSTEPS + ks) * 512);
      wr1[i] = *(const short8*)(wpw + (long)(1 * GRU_KSTEPS + ks) * 512);
      wr2[i] = *(const short8*)(wpw + (long)(2 * GRU_KSTEPS + ks) * 512);
      wr3[i] = *(const short8*)(wpw + (long)(3 * GRU_KSTEPS + ks) * 512);
      wr4[i] = *(const short8*)(wpw + (long)(4 * GRU_KSTEPS + ks) * 512);
      wr5[i] = *(const short8*)(wpw + (long)(5 * GRU_KSTEPS + ks) * 512);
    }

    const int gofs = (b << 4) + u_local;
    for (int t = 0; t < LL; ++t) {
      float gx_r = 0.f, gx_z = 0.f, gx_n = 0.f;
      if (w < 4) {
        const long gbase = ((long)(t * 64 + blk) * 3) << 8;
        gx_r = bf2f(__builtin_nontemporal_load(gix2 + gbase + gofs));
        gx_z = bf2f(__builtin_nontemporal_load(gix2 + gbase + 256 + gofs));
        gx_n = bf2f(__builtin_nontemporal_load(gix2 + gbase + 512 + gofs));
      }
      if (t > 0) {
        if (w == 0) {
          const unsigned tgt = (unsigned)t;
          while (1) {
            unsigned f = __hip_atomic_load(&flags[lane << 4], __ATOMIC_RELAXED,
                                           __HIP_MEMORY_SCOPE_AGENT);
            if (__all((int)(f >= tgt))) break;
            __builtin_amdgcn_s_sleep(1);
          }
        }
        __syncthreads();
      }

      const ushort* hb = hbuf + ((long)t << 14);
      f32x4 acc0 = {0.f,0.f,0.f,0.f}, acc1 = acc0, acc2 = acc0,
            acc3 = acc0, acc4 = acc0, acc5 = acc0;
#pragma unroll
      for (int i = 0; i < 4; ++i) {
        const int ks = i * 8 + w;
        unsigned long long* ap = (unsigned long long*)(hb + (((long)ks * 64 + lane) << 3));
        union { unsigned long long q[2]; short8 v; } cv;
        cv.q[0] = __hip_atomic_load(ap,     __ATOMIC_RELAXED, __HIP_MEMORY_SCOPE_AGENT);
        cv.q[1] = __hip_atomic_load(ap + 1, __ATOMIC_RELAXED, __HIP_MEMORY_SCOPE_AGENT);
        acc0 = __builtin_amdgcn_mfma_f32_16x16x32_bf16(cv.v, wr0[i], acc0, 0, 0, 0);
        acc1 = __builtin_amdgcn_mfma_f32_16x16x32_bf16(cv.v, wr1[i], acc1, 0, 0, 0);
        acc2 = __builtin_amdgcn_mfma_f32_16x16x32_bf16(cv.v, wr2[i], acc2, 0, 0, 0);
        acc3 = __builtin_amdgcn_mfma_f32_16x16x32_bf16(cv.v, wr3[i], acc3, 0, 0, 0);
        acc4 = __builtin_amdgcn_mfma_f32_16x16x32_bf16(cv.v, wr4[i], acc4, 0, 0, 0);
        acc5 = __builtin_amdgcn_mfma_f32_16x16x32_bf16(cv.v, wr5[i], acc5, 0, 0, 0);
      }
#pragma unroll
      for (int j = 0; j < 4; ++j) {
        red[((w * 6 + 0) << 8) + (j << 6) + lane] = acc0[j];
        red[((w * 6 + 1) << 8) + (j << 6) + lane] = acc1[j];
        red[((w * 6 + 2) << 8) + (j << 6) + lane] = acc2[j];
        red[((w * 6 + 3) << 8) + (j << 6) + lane] = acc3[j];
        red[((w * 6 + 4) << 8) + (j << 6) + lane] = acc4[j];
        red[((w * 6 + 5) << 8) + (j << 6) + lane] = acc5[j];
      }
      __syncthreads();
      ushort h16 = 0;
      if (w < 4) {
        float v0 = 0.f, v1 = 0.f, v2 = 0.f, v3 = 0.f, v4 = 0.f, v5 = 0.f;
#pragma unroll
        for (int wv = 0; wv < 8; ++wv) {
          const int base = ((wv * 6) << 8) + (j_c << 6) + lane;
          v0 += red[base];
          v1 += red[base + 256];
          v2 += red[base + 512];
          v3 += red[base + 768];
          v4 += red[base + 1024];
          v5 += red[base + 1280];
        }
        const float rg = 1.f / (1.f + __expf(-(gx_r + v0 + v3 + bhr)));
        const float zg = 1.f / (1.f + __expf(-(gx_z + v1 + v4 + bhz)));
        const float nx = gx_n + v2 + rg * (v5 + bhn);
        const float ng = 1.f - 2.f / (__expf(2.f * nx) + 1.f);
        const float hn = (1.f - zg) * ng + zg * hold;
        hold = hn;
        h16 = f2bf(hn);
      }
      if (t < LL - 1) {
        if (w < 4)
          __hip_atomic_store(hbuf + (((long)(t + 1)) << 14) + hout_off, h16,
                             __ATOMIC_RELAXED, __HIP_MEMORY_SCOPE_AGENT);
        __syncthreads();  // drains vmcnt for every wave before the flag
        if (tid == 0)
          __hip_atomic_store(&flags[blk << 4], (unsigned)(t + 1), __ATOMIC_RELAXED,
                             __HIP_MEMORY_SCOPE_AGENT);
      }
      // h_seq publish: agent-atomic (reaches L3), off the critical path.
      if (w < 4)
        __hip_atomic_store(h_seq + ((long)b * LL + t) * DD2 + u, h16,
                           __ATOMIC_RELAXED, __HIP_MEMORY_SCOPE_AGENT);
    }
    // Final publish: drain h_seq[510..511], then flag=600 (>= any gate).
    __syncthreads();
    if (tid == 0)
      __hip_atomic_store(&flags[blk << 4], 600u, __ATOMIC_RELAXED,
                         __HIP_MEMORY_SCOPE_AGENT);
  } else {
    // ------------------------- worker role -------------------------
    const int wid = blockIdx.x - 64;
    // main pairs: t0 in {0,128,256}
    for (int i = wid; i < 3072; i += 192) {
      const int nb = i & 63;
      const int rest = i >> 6;
      const int b = rest & 15;
      const int t0 = (rest >> 4) * 128;
      wait_flags((unsigned)(t0 + 129), tid, flags);
      do_pair<128>(b * 512 + t0, nb * 128, h_seq, mdnsg, mdnmu, sg_b, mu_b,
                   outS, outM, smem, tid);
    }
    // late pairs: rows 384..447 (MR=64), gated mid-scan at flag 449
    for (int i = wid; i < 1024; i += 192) {
      const int nb = i & 63;
      const int b = (i >> 6) & 15;
      wait_flags(449u, tid, flags);
      do_pair<64>(b * 512 + 384, nb * 128, h_seq, mdnsg, mdnmu, sg_b, mu_b,
                  outS, outM, smem, tid);
    }
  }
  // ------------------------- tail (all 256 blocks): rows 448..511 ----------
  for (int i = blockIdx.x; i < 1024; i += 256) {
    const int nb = i & 63;
    const int b = (i >> 6) & 15;
    wait_flags(513u, tid, flags);
    do_pair<64>(b * 512 + 448, nb * 128, h_seq, mdnsg, mdnmu, sg_b, mu_b,
                outS, outM, smem, tid);
  }
  // ------------------------- w_head fold (all 256 blocks) ------------------
  // (flag >= 513 already established by the tail loop's gate.)
  {
    const int lane = tid & 63, w = tid >> 6;
#pragma unroll
    for (int i = 0; i < 4; ++i) {
      const long r = (long)blockIdx.x * 32 + i * 8 + w;
      float s[KMIX];
#pragma unroll
      for (int k = 0; k < KMIX; k++) s[k] = 0.f;
      for (int u = lane; u < DD2; u += 64) {
        float hv = bf2f(h_seq[r * DD2 + u]);
#pragma unroll
        for (int k = 0; k < KMIX; k++) s[k] += hv * ww[(long)k * DD2 + u];
      }
#pragma unroll
      for (int k = 0; k < KMIX; k++)
#pragma unroll
        for (int o = 32; o; o >>= 1) s[k] += __shfl_xor(s[k], o);
#pragma unroll
      for (int k = 0; k < KMIX; k++) s[k] += wb[k];
      float m = s[0];
#pragma unroll
      for (int k = 1; k < KMIX; k++) m = fmaxf(m, s[k]);
      float esum = 0.f;
#pragma unroll
      for (int k = 0; k < KMIX; k++) { s[k] = expf(s[k] - m); esum += s[k]; }
      float mine = 0.f;
#pragma unroll
      for (int k = 0; k < KMIX; k++) if (lane == k) mine = s[k];
      if (lane < KMIX) outW[r * KMIX + lane] = mine / esum;
    }
  }
}

// ---------------------------------------------------------------------------
extern "C" void kernel_launch(void* const* d_in, const int* in_sizes, int n_in,
                              void* d_out, int out_size, void* d_ws, size_t ws_size,
                              hipStream_t stream) {
  const float* h_text     = (const float*)d_in[0];
  const float* conv1_w    = (const float*)d_in[1];
  const float* conv1_b    = (const float*)d_in[2];
  const float* ln1_g      = (const float*)d_in[3];
  const float* ln1_b      = (const float*)d_in[4];
  const float* conv2_w    = (const float*)d_in[5];
  const float* conv2_b    = (const float*)d_in[6];
  const float* ln2_g      = (const float*)d_in[7];
  const float* ln2_b      = (const float*)d_in[8];
  const float* w_ih       = (const float*)d_in[9];
  const float* w_hh       = (const float*)d_in[10];
  const float* b_ih       = (const float*)d_in[11];
  const float* b_hh       = (const float*)d_in[12];
  const float* mdn_w_w    = (const float*)d_in[13];
  const float* mdn_w_b    = (const float*)d_in[14];
  const float* mdn_sig_w  = (const float*)d_in[15];
  const float* mdn_sig_b  = (const float*)d_in[16];
  const float* mdn_mu_w   = (const float*)d_in[17];
  const float* mdn_mu_b   = (const float*)d_in[18];
  float* out = (float*)d_out;

  char* ws = (char*)d_ws;
  size_t off = 0;
  auto take = [&](size_t bytes) {
    void* p = ws + off;
    off += (bytes + 255) & ~(size_t)255;
    return p;
  };
  ushort* xpad1  = (ushort*)take((size_t)BB * LPAD * DD * 2);
  ushort* xpad2  = (ushort*)take((size_t)BB * LPAD * DD * 2);
  ushort* wpack1 = (ushort*)take((size_t)DD * DD * 9 * 2);
  ushort* wpack2 = (ushort*)take((size_t)DD * DD * 9 * 2);
  float*  ybuf   = (float*) take((size_t)BB * LL * DD * 4);
  ushort* x2     = (ushort*)take((size_t)BB * LL * DD * 2);
  ushort* wihx   = (ushort*)take((size_t)3 * DD2 * DD * 2);
  ushort* gix    = (ushort*)take((size_t)BB * LL * 3 * DD2 * 2);   // packed layout
  ushort* Wp     = (ushort*)take((size_t)64 * 6 * GRU_KSTEPS * 64 * 8 * 2);
  ushort* hseq   = (ushort*)take((size_t)BB * LL * DD2 * 2);
  ushort* mdnmu  = (ushort*)take((size_t)KMIX * DD2 * DD2 * 2);
  ushort* mdnsg  = (ushort*)take((size_t)KMIX * DD2 * DD2 * 2);
  ushort* hbuf   = (ushort*)take((size_t)512 * 16384 * 2);   // 512 write-once frag buffers
  unsigned* flags = (unsigned*)take(64 * 16 * 4);            // 64 flags, 64B-padded lines

  const long sigma_off = (long)BB * LL * KMIX;                    // 65536
  const long mu_off    = sigma_off + (long)BB * LL * KMIX * DD2;  // 67174400

  // --- all prep / packing in ONE dispatch ---
  mega_prep<<<2048, 256, 0, stream>>>(h_text, xpad1, xpad2,
                                      conv1_w, wpack1, conv2_w, wpack2,
                                      w_ih, wihx, w_hh, b_hh, Wp,
                                      mdn_mu_w, mdnmu, mdn_sig_w, mdnsg,
                                      hbuf, flags);

  // --- conv block 1: y = conv(xpad1) + b ; LN+ReLU -> xpad2 ---
  conv_gemm<<<dim3(4, 128), 256, 0, stream>>>(xpad1, wpack1, ybuf, conv1_b);
  ln_relu<1><<<BB * LL, 256, 0, stream>>>(ybuf, ln1_g, ln1_b, xpad2);

  // --- conv block 2 -> x2 (GRU input, plain bf16 [8192,512]) ---
  conv_gemm<<<dim3(4, 128), 256, 0, stream>>>(xpad2, wpack2, ybuf, conv2_b);
  ln_relu<0><<<BB * LL, 256, 0, stream>>>(ybuf, ln2_g, ln2_b, x2);

  // --- gi_x = x2 @ w_ih[:, :512]^T + b_ih -> PACKED gix layout ---
  gix_gemm<<<dim3(24, 64), 256, 0, stream>>>(x2, wihx, gix, b_ih);

  // --- fused persistent scan + MDN heads + w_head (single dispatch) ---
  fused_scan_mdn<<<256, 512, 0, stream>>>(Wp, gix, b_hh, hbuf, hseq, flags,
                                          mdnsg, mdnmu, mdn_sig_b, mdn_mu_b,
                                          out + sigma_off, out + mu_off,
                                          mdn_w_w, mdn_w_b, out);
}